// Round 14
// baseline (559.221 us; speedup 1.0000x reference)
//
#include <hip/hip_runtime.h>

// Inputs: floats fp32, ints int32. Outputs fp32 (verified round 7).
// Round 14: two-level binned CSR build replaces the random-scatter k_scatter
//           (55 us, 52.7 MB HBM writes for a 3.2 MB payload = 64B-line
//           amplification). Phase 1 appends packed (dstLocal,src) densely per
//           128-node bucket; phase 2 (block per bucket) places into nbr within
//           an 8 KB region via LDS cursors. cursor[] is no longer mutated.

typedef unsigned short ushort_t;
typedef __attribute__((ext_vector_type(8))) short bf16x8;   // 8 bf16 (MFMA A/B frag)
typedef __attribute__((ext_vector_type(4))) float floatx4;  // MFMA C/D frag

// ---------- helpers ----------
__device__ __forceinline__ float b2f(ushort_t u) {
    union { unsigned int i; float f; } v; v.i = ((unsigned int)u) << 16; return v.f;
}
__device__ __forceinline__ ushort_t f2b(float f) {
    union { float f; unsigned int i; } v; v.f = f;
    unsigned int x = v.i;
    return (ushort_t)((x + 0x7FFFu + ((x >> 16) & 1u)) >> 16);   // RTNE
}
__device__ __forceinline__ float gelu_f(float x) {
    return 0.5f * x * (1.0f + erff(x * 0.70710678118654752440f)); // exact gelu
}
__device__ __forceinline__ float waveReduceSum(float v) {
#pragma unroll
    for (int o = 32; o; o >>= 1) v += __shfl_xor(v, o, 64);
    return v;
}
__device__ __forceinline__ float waveReduceMax(float v) {
#pragma unroll
    for (int o = 32; o; o >>= 1) v = fmaxf(v, __shfl_xor(v, o, 64));
    return v;
}

// ---------- 0. Wt[n][k] = bf16 concat-transpose of Wl;Wr ----------
__global__ void k_prep(const float* __restrict__ Wl, const float* __restrict__ Wr,
                       ushort_t* __restrict__ Wt) {
    int id = blockIdx.x * 256 + threadIdx.x;   // 128*256 = 32768
    if (id >= 32768) return;
    int n = id >> 8, k = id & 255;
    float v = (k < 128) ? Wl[k * 128 + n] : Wr[(k - 128) * 128 + n];
    Wt[n * 256 + k] = f2b(v);
}

// ---------- 1. h = layernorm(x, w, b) -> bf16  (one wave per row) ----------
__global__ void k_ln1(const float* __restrict__ x, const float* __restrict__ w,
                      const float* __restrict__ b, ushort_t* __restrict__ hb, int N) {
    int row  = (blockIdx.x * blockDim.x + threadIdx.x) >> 6;
    int lane = threadIdx.x & 63;
    if (row >= N) return;
    size_t base = (size_t)row * 128;
    float2 xv = ((const float2*)(x + base))[lane];
    float v0 = xv.x, v1 = xv.y;
    float s  = waveReduceSum(v0 + v1);
    float s2 = waveReduceSum(v0 * v0 + v1 * v1);
    float mu = s * (1.0f / 128.0f);
    float var = s2 * (1.0f / 128.0f) - mu * mu;
    float rstd = 1.0f / sqrtf(var + 1e-5f);
    int d = lane * 2;
    ushort2 ov;
    ov.x = f2b((v0 - mu) * rstd * w[d]     + b[d]);
    ov.y = f2b((v1 - mu) * rstd * w[d + 1] + b[d + 1]);
    ((ushort2*)(hb + base))[lane] = ov;
}

// ---------- 2. deg[dst] += 1 ----------
__global__ void k_deg(const int* __restrict__ ei, int* __restrict__ deg, int E) {
    int e = blockIdx.x * blockDim.x + threadIdx.x;
    if (e < E) atomicAdd(&deg[ei[E + e]], 1);    // edge_index row 1 = dst
}

// ---------- 3. scan: chunk sums -> chunk scan -> per-element cursor (row starts) -----
__global__ void k_chunksum(const int* __restrict__ deg, int* __restrict__ csum, int N) {
    int i = blockIdx.x * 256 + threadIdx.x;
    int v = (i < N) ? deg[i] : 0;
#pragma unroll
    for (int o = 32; o; o >>= 1) v += __shfl_xor(v, o, 64);
    __shared__ int buf[4];
    int lane = threadIdx.x & 63, wv = threadIdx.x >> 6;
    if (lane == 0) buf[wv] = v;
    __syncthreads();
    if (threadIdx.x == 0) csum[blockIdx.x] = buf[0] + buf[1] + buf[2] + buf[3];
}
__global__ void k_chunkscan(const int* __restrict__ csum, int* __restrict__ coff, int nch) {
    int t = threadIdx.x;
    int v = (t < nch) ? csum[t] : 0;
    __shared__ int sb[256];
    sb[t] = v; __syncthreads();
    for (int o = 1; o < 256; o <<= 1) {
        int a = (t >= o) ? sb[t - o] : 0;
        __syncthreads();
        sb[t] += a;
        __syncthreads();
    }
    coff[t] = sb[t] - v;    // exclusive
}
__global__ void k_cursor(const int* __restrict__ deg, const int* __restrict__ coff,
                         int* __restrict__ cursor, int N) {
    int t = threadIdx.x;
    int i = blockIdx.x * 256 + t;
    int v = (i < N) ? deg[i] : 0;
    __shared__ int sb[256];
    sb[t] = v; __syncthreads();
    for (int o = 1; o < 256; o <<= 1) {
        int a = (t >= o) ? sb[t - o] : 0;
        __syncthreads();
        sb[t] += a;
        __syncthreads();
    }
    if (i < N) cursor[i] = sb[t] - v + coff[blockIdx.x];   // exclusive scan = row start
}

// ---------- 4a. bucket cursors = region starts (bucket b = nodes [b*128,(b+1)*128)) --
__global__ void k_binit(const int* __restrict__ cursor, int* __restrict__ bcur,
                        int nb, int N, int E) {
    int b = blockIdx.x * blockDim.x + threadIdx.x;
    if (b > nb) return;
    int node = b << 7;
    bcur[b] = (node < N) ? cursor[node] : E;
}

// ---------- 4b. phase 1: append packed (dstLocal<<25 | src) into bucket regions ------
__global__ void k_bscatter(const int* __restrict__ ei, int* __restrict__ bcur,
                           unsigned int* __restrict__ packed, int E) {
    int e = blockIdx.x * blockDim.x + threadIdx.x;
    if (e >= E) return;
    int s = ei[e], d = ei[E + e];
    int pos = atomicAdd(&bcur[d >> 7], 1);
    packed[pos] = ((unsigned int)(d & 127) << 25) | (unsigned int)s;
}

// ---------- 4c. phase 2: per-bucket placement into nbr (8 KB region, LDS cursors) ----
__global__ void __launch_bounds__(256) k_bsort(
    const unsigned int* __restrict__ packed, const int* __restrict__ cursor,
    int* __restrict__ nbr, int N, int E) {
    __shared__ int lcur[128];
    int b = blockIdx.x, t = threadIdx.x;
    int node0 = b << 7;
    if (t < 128) {
        int node = node0 + t;
        lcur[t] = (node < N) ? cursor[node] : 0;
    }
    __syncthreads();
    int gstart = cursor[node0];                   // node0 < N by grid construction
    int next = node0 + 128;
    int gend = (next < N) ? cursor[next] : E;
    for (int i = gstart + t; i < gend; i += 256) {
        unsigned int p = packed[i];
        int pos = atomicAdd(&lcur[p >> 25], 1);   // LDS atomic
        nbr[pos] = (int)(p & 0x1FFFFFFu);
    }
}

// ---------- 5. CSR gather + mean, bf16 (one wave per node; cursor = row START) -------
__global__ void k_aggcsr(const ushort_t* __restrict__ hb, const int* __restrict__ cursor,
                         const int* __restrict__ deg, const int* __restrict__ nbr,
                         ushort_t* __restrict__ meanb, int N) {
    int node = (blockIdx.x * blockDim.x + threadIdx.x) >> 6;
    int lane = threadIdx.x & 63;
    if (node >= N) return;
    int dg = deg[node];
    int st = cursor[node];
    float a0 = 0.f, a1 = 0.f;
    int j = 0;
    for (; j + 4 <= dg; j += 4) {        // 4 independent row gathers in flight
        int s0 = nbr[st + j],     s1 = nbr[st + j + 1];
        int s2 = nbr[st + j + 2], s3 = nbr[st + j + 3];
        ushort2 v0 = ((const ushort2*)(hb + (size_t)s0 * 128))[lane];
        ushort2 v1 = ((const ushort2*)(hb + (size_t)s1 * 128))[lane];
        ushort2 v2 = ((const ushort2*)(hb + (size_t)s2 * 128))[lane];
        ushort2 v3 = ((const ushort2*)(hb + (size_t)s3 * 128))[lane];
        a0 += b2f(v0.x) + b2f(v1.x) + b2f(v2.x) + b2f(v3.x);
        a1 += b2f(v0.y) + b2f(v1.y) + b2f(v2.y) + b2f(v3.y);
    }
    for (; j < dg; j++) {
        int s = nbr[st + j];
        ushort2 v = ((const ushort2*)(hb + (size_t)s * 128))[lane];
        a0 += b2f(v.x); a1 += b2f(v.y);
    }
    float inv = 1.0f / fmaxf((float)dg, 1.0f);
    ushort2 ov; ov.x = f2b(a0 * inv); ov.y = f2b(a1 * inv);
    ((ushort2*)(meanb + (size_t)node * 128))[lane] = ov;
}

// ---------- 6. MFMA: h2 = [mean|h] @ [Wl;Wr] + b_l ; LN ; gelu ; gate ----------
__global__ void __launch_bounds__(256) k_gemm(
    const ushort_t* __restrict__ meanb, ushort_t* __restrict__ hb,
    const ushort_t* __restrict__ Wt, const float* __restrict__ bl,
    const float* __restrict__ lnw, const float* __restrict__ lnb,
    const float* __restrict__ gw, const float* __restrict__ gb,
    float* __restrict__ gate, int N) {
    __shared__ ushort_t A[16][264];   // [m][k], pad 264
    __shared__ float H2[16][132];
    int t = threadIdx.x;
    int row0 = blockIdx.x * 16;
    {   // stage A tile
        int r = t >> 4, i = t & 15;
        int row = row0 + r; if (row >= N) row = N - 1;
        *(bf16x8*)&A[r][i * 8]       = *(const bf16x8*)(meanb + (size_t)row * 128 + i * 8);
        *(bf16x8*)&A[r][128 + i * 8] = *(const bf16x8*)(hb    + (size_t)row * 128 + i * 8);
    }
    __syncthreads();
    int w = t >> 6, l = t & 63;
    int m16 = l & 15, quad = l >> 4;
    int n0 = w * 32 + m16;
    int n1 = n0 + 16;
    floatx4 acc0 = {0.f, 0.f, 0.f, 0.f}, acc1 = {0.f, 0.f, 0.f, 0.f};
    for (int ks = 0; ks < 256; ks += 32) {
        bf16x8 a  = *(const bf16x8*)&A[m16][ks + quad * 8];
        bf16x8 b0 = *(const bf16x8*)(Wt + (size_t)n0 * 256 + ks + quad * 8);
        bf16x8 b1 = *(const bf16x8*)(Wt + (size_t)n1 * 256 + ks + quad * 8);
        acc0 = __builtin_amdgcn_mfma_f32_16x16x32_bf16(a, b0, acc0, 0, 0, 0);
        acc1 = __builtin_amdgcn_mfma_f32_16x16x32_bf16(a, b1, acc1, 0, 0, 0);
    }
#pragma unroll
    for (int i = 0; i < 4; i++) {
        H2[quad * 4 + i][n0] = acc0[i];
        H2[quad * 4 + i][n1] = acc1[i];
    }
    __syncthreads();
    int d = l * 2;
    float bb0 = bl[d],  bb1 = bl[d + 1];
    float lw0 = lnw[d], lw1 = lnw[d + 1];
    float lb0 = lnb[d], lb1 = lnb[d + 1];
    float gw0 = gw[d],  gw1 = gw[d + 1];
    float gbias = gb[0];
#pragma unroll
    for (int rr = 0; rr < 4; rr++) {
        int r = w * 4 + rr;
        int row = row0 + r;
        if (row >= N) break;
        float v0 = H2[r][d] + bb0, v1 = H2[r][d + 1] + bb1;
        float s  = waveReduceSum(v0 + v1);
        float s2 = waveReduceSum(v0 * v0 + v1 * v1);
        float mu = s * (1.f / 128.f);
        float var = s2 * (1.f / 128.f) - mu * mu;
        float rstd = 1.0f / sqrtf(var + 1e-5f);
        float g0 = gelu_f((v0 - mu) * rstd * lw0 + lb0);
        float g1 = gelu_f((v1 - mu) * rstd * lw1 + lb1);
        float gp = waveReduceSum(g0 * gw0 + g1 * gw1);
        ushort2 ov; ov.x = f2b(g0); ov.y = f2b(g1);
        ((ushort2*)(hb + (size_t)row * 128))[l] = ov;    // h3 in place (bf16)
        if (l == 0) gate[row] = gp + gbias;
    }
}

// ---------- 7. segment boundaries from sorted batch ----------
__global__ void k_segstart(const int* __restrict__ batch, int* __restrict__ segstart,
                           int N, int G) {
    int i = blockIdx.x * blockDim.x + threadIdx.x;
    if (i >= N) return;
    int b = batch[i];
    if (i == 0) {
        for (int g = 0; g <= b; g++) segstart[g] = 0;
    } else {
        int pb = batch[i - 1];
        for (int g = pb + 1; g <= b; g++) segstart[g] = i;
    }
    if (i == N - 1) {
        for (int g = b + 1; g <= G; g++) segstart[g] = N;
    }
}

// ---------- 8. softmax over segment + weighted pool (128-thread block / graph) -------
__global__ void __launch_bounds__(128) k_attn(
    const float* __restrict__ gate, const ushort_t* __restrict__ h3b,
    const int* __restrict__ segstart,
    float* __restrict__ ge_out, float* __restrict__ attn_out, int G) {
    int g = blockIdx.x, t = threadIdx.x;
    int s0 = segstart[g], s1 = segstart[g + 1];
    if (s1 <= s0) {                      // empty segment -> zeros
        ge_out[(size_t)g * 128 + t] = 0.0f;
        return;
    }
    int lane = t & 63, wv = t >> 6;
    __shared__ float wbuf[2];
    __shared__ float pbuf[128];
    float m = -3.0e38f;
    for (int i = s0 + t; i < s1; i += 128) m = fmaxf(m, gate[i]);
    m = waveReduceMax(m);
    if (lane == 0) wbuf[wv] = m;
    __syncthreads();
    m = fmaxf(wbuf[0], wbuf[1]);
    __syncthreads();
    float dsum = 0.f;
    for (int i = s0 + t; i < s1; i += 128) dsum += expf(gate[i] - m);
    dsum = waveReduceSum(dsum);
    if (lane == 0) wbuf[wv] = dsum;
    __syncthreads();
    float inv = 1.0f / (wbuf[0] + wbuf[1]);
    float acc = 0.f;
    for (int base = s0; base < s1; base += 128) {
        int n = min(128, s1 - base);
        __syncthreads();
        if (t < n) {
            float p = expf(gate[base + t] - m) * inv;
            pbuf[t] = p;
            attn_out[base + t] = p;
        }
        __syncthreads();
        for (int j = 0; j < n; j++)
            acc += pbuf[j] * b2f(h3b[(size_t)(base + j) * 128 + t]);
    }
    ge_out[(size_t)g * 128 + t] = acc;
}

// ---------- 9. tail: msg gelu-GEMM + feat gelu-GEMM + concat-LN + logit ----------
__global__ void __launch_bounds__(128) k_tail(
    const float* __restrict__ text, const float* __restrict__ feats,
    const float* __restrict__ msgW, const float* __restrict__ msgb,
    const float* __restrict__ featW, const float* __restrict__ featb,
    const float* __restrict__ gwt, const float* __restrict__ mixw,
    const float* __restrict__ mixb, const float* __restrict__ fc1W,
    const float* __restrict__ fc1b, const float* __restrict__ ge,
    float* __restrict__ logits, int G) {
    int g = blockIdx.x, t = threadIdx.x;
    __shared__ float txt[768];
    __shared__ float rbuf[4];
    for (int i = t; i < 768; i += 128) txt[i] = text[(size_t)g * 768 + i];
    __syncthreads();
    float am = msgb[t];
    for (int k = 0; k < 768; k += 4) {
        float4 a = *(const float4*)&txt[k];
        am += a.x * msgW[(k + 0) * 128 + t] + a.y * msgW[(k + 1) * 128 + t]
            + a.z * msgW[(k + 2) * 128 + t] + a.w * msgW[(k + 3) * 128 + t];
    }
    float me = gelu_f(am);
    float af = featb[t];
#pragma unroll
    for (int k = 0; k < 14; k++) af += feats[g * 14 + k] * featW[k * 128 + t];
    float fe = gelu_f(af);
    float e0 = gwt[0] * ge[(size_t)g * 128 + t];
    float ps = e0 + me + fe, ps2 = e0 * e0 + me * me + fe * fe;
    int lane = t & 63, w = t >> 6;
    float r1 = waveReduceSum(ps), r2 = waveReduceSum(ps2);
    if (lane == 0) { rbuf[w] = r1; rbuf[2 + w] = r2; }
    __syncthreads();
    float S = rbuf[0] + rbuf[1], S2 = rbuf[2] + rbuf[3];
    float mu = S * (1.f / 384.f);
    float var = S2 * (1.f / 384.f) - mu * mu;
    float rstd = 1.0f / sqrtf(var + 1e-5f);
    float n0 = (e0 - mu) * rstd * mixw[t]       + mixb[t];
    float n1 = (me - mu) * rstd * mixw[128 + t] + mixb[128 + t];
    float n2 = (fe - mu) * rstd * mixw[256 + t] + mixb[256 + t];
    float lp = n0 * fc1W[t] + n1 * fc1W[128 + t] + n2 * fc1W[256 + t];
    __syncthreads();
    float r3 = waveReduceSum(lp);
    if (lane == 0) rbuf[w] = r3;
    __syncthreads();
    if (t == 0) logits[g] = rbuf[0] + rbuf[1] + fc1b[0];
}

// ---------- launch ----------
extern "C" void kernel_launch(void* const* d_in, const int* in_sizes, int n_in,
                              void* d_out, int out_size, void* d_ws, size_t ws_size,
                              hipStream_t stream) {
    const float* x     = (const float*)d_in[0];
    const int*   ei    = (const int*)d_in[1];
    const int*   batch = (const int*)d_in[2];
    const float* text  = (const float*)d_in[4];
    const float* feats = (const float*)d_in[5];
    const float* lnpw  = (const float*)d_in[6];
    const float* lnpb  = (const float*)d_in[7];
    const float* Wl    = (const float*)d_in[8];
    const float* bl    = (const float*)d_in[9];
    const float* Wr    = (const float*)d_in[10];
    const float* lncw  = (const float*)d_in[11];
    const float* lncb  = (const float*)d_in[12];
    const float* gatew = (const float*)d_in[13];
    const float* gateb = (const float*)d_in[14];
    const float* gwt   = (const float*)d_in[15];
    const float* msgW  = (const float*)d_in[16];
    const float* msgb  = (const float*)d_in[17];
    const float* featW = (const float*)d_in[18];
    const float* featb = (const float*)d_in[19];
    const float* mixw  = (const float*)d_in[20];
    const float* mixb  = (const float*)d_in[21];
    const float* fc1W  = (const float*)d_in[22];
    const float* fc1b  = (const float*)d_in[23];

    int N = in_sizes[0] / 128;
    int E = in_sizes[1] / 2;
    int G = in_sizes[4] / 768;

    char* wp = (char*)d_ws;
    auto alloc = [&](size_t bytes) -> char* {
        char* p = wp; wp += (bytes + 255) & ~(size_t)255; return p;
    };
    ushort_t* hb     = (ushort_t*)alloc((size_t)N * 128 * 2);   // h -> h3 in place (bf16)
    ushort_t* meanb  = (ushort_t*)alloc((size_t)N * 128 * 2);
    ushort_t* Wt     = (ushort_t*)alloc(128 * 256 * 2);
    float*    gate   = (float*)alloc((size_t)N * 4);
    int*      deg    = (int*)alloc((size_t)N * 4);
    int*      cursor = (int*)alloc((size_t)N * 4);
    int*      nbr    = (int*)alloc((size_t)E * 4);
    unsigned int* packed = (unsigned int*)alloc((size_t)E * 4);
    int*      csum   = (int*)alloc(1024 * 4);
    int*      coff   = (int*)alloc(1024 * 4);
    int*      bcur   = (int*)alloc(4096 * 4);
    int*      segst  = (int*)alloc((size_t)(G + 2) * 4);

    // OUTPUTS fp32, flat in return order:
    float* logits_out = (float*)d_out;                 // [G, 1]
    float* ge_out     = logits_out + G;                // [G, 128]
    float* attn_out   = ge_out + (size_t)G * 128;      // [N, 1]

    int nch = (N + 255) / 256;   // 196 <= 256: one chunkscan block suffices
    int nb  = (N + 127) / 128;   // buckets of 128 nodes (391 for N=50000)

    hipMemsetAsync(deg, 0, (size_t)N * 4, stream);

    k_prep     <<<128,               256, 0, stream>>>(Wl, Wr, Wt);
    k_ln1      <<<(N + 3) / 4,       256, 0, stream>>>(x, lnpw, lnpb, hb, N);
    k_deg      <<<(E + 255) / 256,   256, 0, stream>>>(ei, deg, E);
    k_chunksum <<<nch,               256, 0, stream>>>(deg, csum, N);
    k_chunkscan<<<1,                 256, 0, stream>>>(csum, coff, nch);
    k_cursor   <<<nch,               256, 0, stream>>>(deg, coff, cursor, N);
    k_binit    <<<(nb + 256) / 256,  256, 0, stream>>>(cursor, bcur, nb, N, E);
    k_bscatter <<<(E + 255) / 256,   256, 0, stream>>>(ei, bcur, packed, E);
    k_bsort    <<<nb,                256, 0, stream>>>(packed, cursor, nbr, N, E);
    k_aggcsr   <<<(N + 3) / 4,       256, 0, stream>>>(hb, cursor, deg, nbr, meanb, N);
    k_gemm     <<<(N + 15) / 16,     256, 0, stream>>>(meanb, hb, Wt, bl, lncw, lncb,
                                                       gatew, gateb, gate, N);
    k_segstart <<<(N + 255) / 256,   256, 0, stream>>>(batch, segst, N, G);
    k_attn     <<<G,                 128, 0, stream>>>(gate, hb, segst, ge_out, attn_out, G);
    k_tail     <<<G,                 128, 0, stream>>>(text, feats, msgW, msgb, featW, featb,
                                                       gwt, mixw, mixb, fc1W, fc1b,
                                                       ge_out, logits_out, G);
}

// Round 15
// 310.746 us; speedup vs baseline: 1.7996x; 1.7996x over previous
//
#include <hip/hip_runtime.h>

// Inputs: floats fp32, ints int32. Outputs fp32 (verified round 7).
// Round 15: atomic-free counting-sort CSR build.
//   r13 scatter: 50K-counter atomics, write-amp bound (52.7MB -> 55us).
//   r14 scatter: 391-counter atomics, contention bound (2050/ctr x 137ns -> 281us).
//   Now: per-block LDS histograms -> scanned offsets -> LDS-cursor placement.
//   Zero global atomics in the scatter; dense writes (~5MB).

typedef unsigned short ushort_t;
typedef __attribute__((ext_vector_type(8))) short bf16x8;   // 8 bf16 (MFMA A/B frag)
typedef __attribute__((ext_vector_type(4))) float floatx4;  // MFMA C/D frag

#define NBLK 128      // edge chunks for hist/place
#define MAXNB 1024    // max buckets (N <= 131072)

// ---------- helpers ----------
__device__ __forceinline__ float b2f(ushort_t u) {
    union { unsigned int i; float f; } v; v.i = ((unsigned int)u) << 16; return v.f;
}
__device__ __forceinline__ ushort_t f2b(float f) {
    union { float f; unsigned int i; } v; v.f = f;
    unsigned int x = v.i;
    return (ushort_t)((x + 0x7FFFu + ((x >> 16) & 1u)) >> 16);   // RTNE
}
__device__ __forceinline__ float gelu_f(float x) {
    return 0.5f * x * (1.0f + erff(x * 0.70710678118654752440f)); // exact gelu
}
__device__ __forceinline__ float waveReduceSum(float v) {
#pragma unroll
    for (int o = 32; o; o >>= 1) v += __shfl_xor(v, o, 64);
    return v;
}
__device__ __forceinline__ float waveReduceMax(float v) {
#pragma unroll
    for (int o = 32; o; o >>= 1) v = fmaxf(v, __shfl_xor(v, o, 64));
    return v;
}

// ---------- 0. Wt[n][k] = bf16 concat-transpose of Wl;Wr ----------
__global__ void k_prep(const float* __restrict__ Wl, const float* __restrict__ Wr,
                       ushort_t* __restrict__ Wt) {
    int id = blockIdx.x * 256 + threadIdx.x;   // 128*256 = 32768
    if (id >= 32768) return;
    int n = id >> 8, k = id & 255;
    float v = (k < 128) ? Wl[k * 128 + n] : Wr[(k - 128) * 128 + n];
    Wt[n * 256 + k] = f2b(v);
}

// ---------- 1. h = layernorm(x, w, b) -> bf16  (one wave per row) ----------
__global__ void k_ln1(const float* __restrict__ x, const float* __restrict__ w,
                      const float* __restrict__ b, ushort_t* __restrict__ hb, int N) {
    int row  = (blockIdx.x * blockDim.x + threadIdx.x) >> 6;
    int lane = threadIdx.x & 63;
    if (row >= N) return;
    size_t base = (size_t)row * 128;
    float2 xv = ((const float2*)(x + base))[lane];
    float v0 = xv.x, v1 = xv.y;
    float s  = waveReduceSum(v0 + v1);
    float s2 = waveReduceSum(v0 * v0 + v1 * v1);
    float mu = s * (1.0f / 128.0f);
    float var = s2 * (1.0f / 128.0f) - mu * mu;
    float rstd = 1.0f / sqrtf(var + 1e-5f);
    int d = lane * 2;
    ushort2 ov;
    ov.x = f2b((v0 - mu) * rstd * w[d]     + b[d]);
    ov.y = f2b((v1 - mu) * rstd * w[d + 1] + b[d + 1]);
    ((ushort2*)(hb + base))[lane] = ov;
}

// ---------- 2. deg[dst] += 1 ----------
__global__ void k_deg(const int* __restrict__ ei, int* __restrict__ deg, int E) {
    int e = blockIdx.x * blockDim.x + threadIdx.x;
    if (e < E) atomicAdd(&deg[ei[E + e]], 1);    // edge_index row 1 = dst
}

// ---------- 3. scan: chunk sums -> chunk scan -> per-element cursor (row starts) -----
__global__ void k_chunksum(const int* __restrict__ deg, int* __restrict__ csum, int N) {
    int i = blockIdx.x * 256 + threadIdx.x;
    int v = (i < N) ? deg[i] : 0;
#pragma unroll
    for (int o = 32; o; o >>= 1) v += __shfl_xor(v, o, 64);
    __shared__ int buf[4];
    int lane = threadIdx.x & 63, wv = threadIdx.x >> 6;
    if (lane == 0) buf[wv] = v;
    __syncthreads();
    if (threadIdx.x == 0) csum[blockIdx.x] = buf[0] + buf[1] + buf[2] + buf[3];
}
__global__ void k_chunkscan(const int* __restrict__ csum, int* __restrict__ coff, int nch) {
    int t = threadIdx.x;
    int v = (t < nch) ? csum[t] : 0;
    __shared__ int sb[256];
    sb[t] = v; __syncthreads();
    for (int o = 1; o < 256; o <<= 1) {
        int a = (t >= o) ? sb[t - o] : 0;
        __syncthreads();
        sb[t] += a;
        __syncthreads();
    }
    coff[t] = sb[t] - v;    // exclusive
}
__global__ void k_cursor(const int* __restrict__ deg, const int* __restrict__ coff,
                         int* __restrict__ cursor, int N) {
    int t = threadIdx.x;
    int i = blockIdx.x * 256 + t;
    int v = (i < N) ? deg[i] : 0;
    __shared__ int sb[256];
    sb[t] = v; __syncthreads();
    for (int o = 1; o < 256; o <<= 1) {
        int a = (t >= o) ? sb[t - o] : 0;
        __syncthreads();
        sb[t] += a;
        __syncthreads();
    }
    if (i < N) cursor[i] = sb[t] - v + coff[blockIdx.x];   // exclusive scan = row start
}

// ---------- 4a. per-chunk bucket histograms: bhist[b*NBLK + blk] (bucket-major) ------
__global__ void __launch_bounds__(256) k_hist(
    const int* __restrict__ ei, int* __restrict__ bhist, int E, int nb, int chunk) {
    __shared__ int hist[MAXNB];
    int blk = blockIdx.x, t = threadIdx.x;
    for (int i = t; i < nb; i += 256) hist[i] = 0;
    __syncthreads();
    int e0 = blk * chunk, e1 = min(e0 + chunk, E);
    for (int e = e0 + t; e < e1; e += 256)
        atomicAdd(&hist[ei[E + e] >> 7], 1);
    __syncthreads();
    for (int i = t; i < nb; i += 256) bhist[i * NBLK + blk] = hist[i];
}

// ---------- 4b. scan per bucket over chunks: boff[blk*nb + b] (block-major) ----------
__global__ void __launch_bounds__(256) k_bscan(
    const int* __restrict__ bhist, const int* __restrict__ cursor,
    int* __restrict__ boff, int nb) {
    int t = threadIdx.x;
    for (int b = t; b < nb; b += 256) {
        int run = cursor[b << 7];            // b<<7 < N by nb construction
        const int* row = bhist + b * NBLK;   // contiguous 512 B
#pragma unroll 8
        for (int blk = 0; blk < NBLK; blk++) {
            boff[blk * nb + b] = run;
            run += row[blk];
        }
    }
}

// ---------- 4c. placement: LDS cursors per chunk, dense per-(chunk,bucket) runs ------
__global__ void __launch_bounds__(256) k_bplace(
    const int* __restrict__ ei, const int* __restrict__ boff,
    unsigned int* __restrict__ packed, int E, int nb, int chunk) {
    __shared__ int lcur[MAXNB];
    int blk = blockIdx.x, t = threadIdx.x;
    for (int i = t; i < nb; i += 256) lcur[i] = boff[blk * nb + i];
    __syncthreads();
    int e0 = blk * chunk, e1 = min(e0 + chunk, E);
    for (int e = e0 + t; e < e1; e += 256) {
        int s = ei[e], d = ei[E + e];
        int pos = atomicAdd(&lcur[d >> 7], 1);      // LDS atomic
        packed[pos] = ((unsigned int)(d & 127) << 25) | (unsigned int)s;
    }
}

// ---------- 4d. per-bucket placement into nbr (8 KB region, LDS node cursors) --------
__global__ void __launch_bounds__(256) k_bsort(
    const unsigned int* __restrict__ packed, const int* __restrict__ cursor,
    int* __restrict__ nbr, int N, int E) {
    __shared__ int lcur[128];
    int b = blockIdx.x, t = threadIdx.x;
    int node0 = b << 7;
    if (t < 128) {
        int node = node0 + t;
        lcur[t] = (node < N) ? cursor[node] : 0;
    }
    __syncthreads();
    int gstart = cursor[node0];
    int next = node0 + 128;
    int gend = (next < N) ? cursor[next] : E;
    for (int i = gstart + t; i < gend; i += 256) {
        unsigned int p = packed[i];
        int pos = atomicAdd(&lcur[p >> 25], 1);     // LDS atomic
        nbr[pos] = (int)(p & 0x1FFFFFFu);
    }
}

// ---------- 5. CSR gather + mean, bf16 (one wave per node; cursor = row START) -------
__global__ void k_aggcsr(const ushort_t* __restrict__ hb, const int* __restrict__ cursor,
                         const int* __restrict__ deg, const int* __restrict__ nbr,
                         ushort_t* __restrict__ meanb, int N) {
    int node = (blockIdx.x * blockDim.x + threadIdx.x) >> 6;
    int lane = threadIdx.x & 63;
    if (node >= N) return;
    int dg = deg[node];
    int st = cursor[node];
    float a0 = 0.f, a1 = 0.f;
    int j = 0;
    for (; j + 4 <= dg; j += 4) {        // 4 independent row gathers in flight
        int s0 = nbr[st + j],     s1 = nbr[st + j + 1];
        int s2 = nbr[st + j + 2], s3 = nbr[st + j + 3];
        ushort2 v0 = ((const ushort2*)(hb + (size_t)s0 * 128))[lane];
        ushort2 v1 = ((const ushort2*)(hb + (size_t)s1 * 128))[lane];
        ushort2 v2 = ((const ushort2*)(hb + (size_t)s2 * 128))[lane];
        ushort2 v3 = ((const ushort2*)(hb + (size_t)s3 * 128))[lane];
        a0 += b2f(v0.x) + b2f(v1.x) + b2f(v2.x) + b2f(v3.x);
        a1 += b2f(v0.y) + b2f(v1.y) + b2f(v2.y) + b2f(v3.y);
    }
    for (; j < dg; j++) {
        int s = nbr[st + j];
        ushort2 v = ((const ushort2*)(hb + (size_t)s * 128))[lane];
        a0 += b2f(v.x); a1 += b2f(v.y);
    }
    float inv = 1.0f / fmaxf((float)dg, 1.0f);
    ushort2 ov; ov.x = f2b(a0 * inv); ov.y = f2b(a1 * inv);
    ((ushort2*)(meanb + (size_t)node * 128))[lane] = ov;
}

// ---------- 6. MFMA: h2 = [mean|h] @ [Wl;Wr] + b_l ; LN ; gelu ; gate ----------
__global__ void __launch_bounds__(256) k_gemm(
    const ushort_t* __restrict__ meanb, ushort_t* __restrict__ hb,
    const ushort_t* __restrict__ Wt, const float* __restrict__ bl,
    const float* __restrict__ lnw, const float* __restrict__ lnb,
    const float* __restrict__ gw, const float* __restrict__ gb,
    float* __restrict__ gate, int N) {
    __shared__ ushort_t A[16][264];   // [m][k], pad 264
    __shared__ float H2[16][132];
    int t = threadIdx.x;
    int row0 = blockIdx.x * 16;
    {   // stage A tile
        int r = t >> 4, i = t & 15;
        int row = row0 + r; if (row >= N) row = N - 1;
        *(bf16x8*)&A[r][i * 8]       = *(const bf16x8*)(meanb + (size_t)row * 128 + i * 8);
        *(bf16x8*)&A[r][128 + i * 8] = *(const bf16x8*)(hb    + (size_t)row * 128 + i * 8);
    }
    __syncthreads();
    int w = t >> 6, l = t & 63;
    int m16 = l & 15, quad = l >> 4;
    int n0 = w * 32 + m16;
    int n1 = n0 + 16;
    floatx4 acc0 = {0.f, 0.f, 0.f, 0.f}, acc1 = {0.f, 0.f, 0.f, 0.f};
    for (int ks = 0; ks < 256; ks += 32) {
        bf16x8 a  = *(const bf16x8*)&A[m16][ks + quad * 8];
        bf16x8 b0 = *(const bf16x8*)(Wt + (size_t)n0 * 256 + ks + quad * 8);
        bf16x8 b1 = *(const bf16x8*)(Wt + (size_t)n1 * 256 + ks + quad * 8);
        acc0 = __builtin_amdgcn_mfma_f32_16x16x32_bf16(a, b0, acc0, 0, 0, 0);
        acc1 = __builtin_amdgcn_mfma_f32_16x16x32_bf16(a, b1, acc1, 0, 0, 0);
    }
#pragma unroll
    for (int i = 0; i < 4; i++) {
        H2[quad * 4 + i][n0] = acc0[i];
        H2[quad * 4 + i][n1] = acc1[i];
    }
    __syncthreads();
    int d = l * 2;
    float bb0 = bl[d],  bb1 = bl[d + 1];
    float lw0 = lnw[d], lw1 = lnw[d + 1];
    float lb0 = lnb[d], lb1 = lnb[d + 1];
    float gw0 = gw[d],  gw1 = gw[d + 1];
    float gbias = gb[0];
#pragma unroll
    for (int rr = 0; rr < 4; rr++) {
        int r = w * 4 + rr;
        int row = row0 + r;
        if (row >= N) break;
        float v0 = H2[r][d] + bb0, v1 = H2[r][d + 1] + bb1;
        float s  = waveReduceSum(v0 + v1);
        float s2 = waveReduceSum(v0 * v0 + v1 * v1);
        float mu = s * (1.f / 128.f);
        float var = s2 * (1.f / 128.f) - mu * mu;
        float rstd = 1.0f / sqrtf(var + 1e-5f);
        float g0 = gelu_f((v0 - mu) * rstd * lw0 + lb0);
        float g1 = gelu_f((v1 - mu) * rstd * lw1 + lb1);
        float gp = waveReduceSum(g0 * gw0 + g1 * gw1);
        ushort2 ov; ov.x = f2b(g0); ov.y = f2b(g1);
        ((ushort2*)(hb + (size_t)row * 128))[l] = ov;    // h3 in place (bf16)
        if (l == 0) gate[row] = gp + gbias;
    }
}

// ---------- 7. segment boundaries from sorted batch ----------
__global__ void k_segstart(const int* __restrict__ batch, int* __restrict__ segstart,
                           int N, int G) {
    int i = blockIdx.x * blockDim.x + threadIdx.x;
    if (i >= N) return;
    int b = batch[i];
    if (i == 0) {
        for (int g = 0; g <= b; g++) segstart[g] = 0;
    } else {
        int pb = batch[i - 1];
        for (int g = pb + 1; g <= b; g++) segstart[g] = i;
    }
    if (i == N - 1) {
        for (int g = b + 1; g <= G; g++) segstart[g] = N;
    }
}

// ---------- 8. softmax over segment + weighted pool (128-thread block / graph) -------
__global__ void __launch_bounds__(128) k_attn(
    const float* __restrict__ gate, const ushort_t* __restrict__ h3b,
    const int* __restrict__ segstart,
    float* __restrict__ ge_out, float* __restrict__ attn_out, int G) {
    int g = blockIdx.x, t = threadIdx.x;
    int s0 = segstart[g], s1 = segstart[g + 1];
    if (s1 <= s0) {                      // empty segment -> zeros
        ge_out[(size_t)g * 128 + t] = 0.0f;
        return;
    }
    int lane = t & 63, wv = t >> 6;
    __shared__ float wbuf[2];
    __shared__ float pbuf[128];
    float m = -3.0e38f;
    for (int i = s0 + t; i < s1; i += 128) m = fmaxf(m, gate[i]);
    m = waveReduceMax(m);
    if (lane == 0) wbuf[wv] = m;
    __syncthreads();
    m = fmaxf(wbuf[0], wbuf[1]);
    __syncthreads();
    float dsum = 0.f;
    for (int i = s0 + t; i < s1; i += 128) dsum += expf(gate[i] - m);
    dsum = waveReduceSum(dsum);
    if (lane == 0) wbuf[wv] = dsum;
    __syncthreads();
    float inv = 1.0f / (wbuf[0] + wbuf[1]);
    float acc = 0.f;
    for (int base = s0; base < s1; base += 128) {
        int n = min(128, s1 - base);
        __syncthreads();
        if (t < n) {
            float p = expf(gate[base + t] - m) * inv;
            pbuf[t] = p;
            attn_out[base + t] = p;
        }
        __syncthreads();
        for (int j = 0; j < n; j++)
            acc += pbuf[j] * b2f(h3b[(size_t)(base + j) * 128 + t]);
    }
    ge_out[(size_t)g * 128 + t] = acc;
}

// ---------- 9. tail: msg gelu-GEMM + feat gelu-GEMM + concat-LN + logit ----------
__global__ void __launch_bounds__(128) k_tail(
    const float* __restrict__ text, const float* __restrict__ feats,
    const float* __restrict__ msgW, const float* __restrict__ msgb,
    const float* __restrict__ featW, const float* __restrict__ featb,
    const float* __restrict__ gwt, const float* __restrict__ mixw,
    const float* __restrict__ mixb, const float* __restrict__ fc1W,
    const float* __restrict__ fc1b, const float* __restrict__ ge,
    float* __restrict__ logits, int G) {
    int g = blockIdx.x, t = threadIdx.x;
    __shared__ float txt[768];
    __shared__ float rbuf[4];
    for (int i = t; i < 768; i += 128) txt[i] = text[(size_t)g * 768 + i];
    __syncthreads();
    float am = msgb[t];
    for (int k = 0; k < 768; k += 4) {
        float4 a = *(const float4*)&txt[k];
        am += a.x * msgW[(k + 0) * 128 + t] + a.y * msgW[(k + 1) * 128 + t]
            + a.z * msgW[(k + 2) * 128 + t] + a.w * msgW[(k + 3) * 128 + t];
    }
    float me = gelu_f(am);
    float af = featb[t];
#pragma unroll
    for (int k = 0; k < 14; k++) af += feats[g * 14 + k] * featW[k * 128 + t];
    float fe = gelu_f(af);
    float e0 = gwt[0] * ge[(size_t)g * 128 + t];
    float ps = e0 + me + fe, ps2 = e0 * e0 + me * me + fe * fe;
    int lane = t & 63, w = t >> 6;
    float r1 = waveReduceSum(ps), r2 = waveReduceSum(ps2);
    if (lane == 0) { rbuf[w] = r1; rbuf[2 + w] = r2; }
    __syncthreads();
    float S = rbuf[0] + rbuf[1], S2 = rbuf[2] + rbuf[3];
    float mu = S * (1.f / 384.f);
    float var = S2 * (1.f / 384.f) - mu * mu;
    float rstd = 1.0f / sqrtf(var + 1e-5f);
    float n0 = (e0 - mu) * rstd * mixw[t]       + mixb[t];
    float n1 = (me - mu) * rstd * mixw[128 + t] + mixb[128 + t];
    float n2 = (fe - mu) * rstd * mixw[256 + t] + mixb[256 + t];
    float lp = n0 * fc1W[t] + n1 * fc1W[128 + t] + n2 * fc1W[256 + t];
    __syncthreads();
    float r3 = waveReduceSum(lp);
    if (lane == 0) rbuf[w] = r3;
    __syncthreads();
    if (t == 0) logits[g] = rbuf[0] + rbuf[1] + fc1b[0];
}

// ---------- launch ----------
extern "C" void kernel_launch(void* const* d_in, const int* in_sizes, int n_in,
                              void* d_out, int out_size, void* d_ws, size_t ws_size,
                              hipStream_t stream) {
    const float* x     = (const float*)d_in[0];
    const int*   ei    = (const int*)d_in[1];
    const int*   batch = (const int*)d_in[2];
    const float* text  = (const float*)d_in[4];
    const float* feats = (const float*)d_in[5];
    const float* lnpw  = (const float*)d_in[6];
    const float* lnpb  = (const float*)d_in[7];
    const float* Wl    = (const float*)d_in[8];
    const float* bl    = (const float*)d_in[9];
    const float* Wr    = (const float*)d_in[10];
    const float* lncw  = (const float*)d_in[11];
    const float* lncb  = (const float*)d_in[12];
    const float* gatew = (const float*)d_in[13];
    const float* gateb = (const float*)d_in[14];
    const float* gwt   = (const float*)d_in[15];
    const float* msgW  = (const float*)d_in[16];
    const float* msgb  = (const float*)d_in[17];
    const float* featW = (const float*)d_in[18];
    const float* featb = (const float*)d_in[19];
    const float* mixw  = (const float*)d_in[20];
    const float* mixb  = (const float*)d_in[21];
    const float* fc1W  = (const float*)d_in[22];
    const float* fc1b  = (const float*)d_in[23];

    int N = in_sizes[0] / 128;
    int E = in_sizes[1] / 2;
    int G = in_sizes[4] / 768;

    char* wp = (char*)d_ws;
    auto alloc = [&](size_t bytes) -> char* {
        char* p = wp; wp += (bytes + 255) & ~(size_t)255; return p;
    };
    ushort_t* hb     = (ushort_t*)alloc((size_t)N * 128 * 2);   // h -> h3 in place (bf16)
    ushort_t* meanb  = (ushort_t*)alloc((size_t)N * 128 * 2);
    ushort_t* Wt     = (ushort_t*)alloc(128 * 256 * 2);
    float*    gate   = (float*)alloc((size_t)N * 4);
    int*      deg    = (int*)alloc((size_t)N * 4);
    int*      cursor = (int*)alloc((size_t)N * 4);
    int*      nbr    = (int*)alloc((size_t)E * 4);
    unsigned int* packed = (unsigned int*)alloc((size_t)E * 4);
    int*      csum   = (int*)alloc(1024 * 4);
    int*      coff   = (int*)alloc(1024 * 4);
    int*      segst  = (int*)alloc((size_t)(G + 2) * 4);

    int nch = (N + 255) / 256;   // 196 <= 256: one chunkscan block suffices
    int nb  = (N + 127) / 128;   // buckets of 128 nodes (391 for N=50000)
    int chunk = (E + NBLK - 1) / NBLK;

    int* bhist = (int*)alloc((size_t)nb * NBLK * 4);   // [b][blk]
    int* boff  = (int*)alloc((size_t)NBLK * nb * 4);   // [blk][b]

    // OUTPUTS fp32, flat in return order:
    float* logits_out = (float*)d_out;                 // [G, 1]
    float* ge_out     = logits_out + G;                // [G, 128]
    float* attn_out   = ge_out + (size_t)G * 128;      // [N, 1]

    hipMemsetAsync(deg, 0, (size_t)N * 4, stream);

    k_prep     <<<128,               256, 0, stream>>>(Wl, Wr, Wt);
    k_ln1      <<<(N + 3) / 4,       256, 0, stream>>>(x, lnpw, lnpb, hb, N);
    k_deg      <<<(E + 255) / 256,   256, 0, stream>>>(ei, deg, E);
    k_chunksum <<<nch,               256, 0, stream>>>(deg, csum, N);
    k_chunkscan<<<1,                 256, 0, stream>>>(csum, coff, nch);
    k_cursor   <<<nch,               256, 0, stream>>>(deg, coff, cursor, N);
    k_hist     <<<NBLK,              256, 0, stream>>>(ei, bhist, E, nb, chunk);
    k_bscan    <<<1,                 256, 0, stream>>>(bhist, cursor, boff, nb);
    k_bplace   <<<NBLK,              256, 0, stream>>>(ei, boff, packed, E, nb, chunk);
    k_bsort    <<<nb,                256, 0, stream>>>(packed, cursor, nbr, N, E);
    k_aggcsr   <<<(N + 3) / 4,       256, 0, stream>>>(hb, cursor, deg, nbr, meanb, N);
    k_gemm     <<<(N + 15) / 16,     256, 0, stream>>>(meanb, hb, Wt, bl, lncw, lncb,
                                                       gatew, gateb, gate, N);
    k_segstart <<<(N + 255) / 256,   256, 0, stream>>>(batch, segst, N, G);
    k_attn     <<<G,                 128, 0, stream>>>(gate, hb, segst, ge_out, attn_out, G);
    k_tail     <<<G,                 128, 0, stream>>>(text, feats, msgW, msgb, featW, featb,
                                                       gwt, mixw, mixb, fc1W, fc1b,
                                                       ge_out, logits_out, G);
}

// Round 16
// 294.662 us; speedup vs baseline: 1.8978x; 1.0546x over previous
//
#include <hip/hip_runtime.h>

// Inputs: floats fp32, ints int32. Outputs fp32 (verified round 7).
// Round 16: launch-count reduction + MLP.
//   - k_deg+k_hist fused (one ei-dst pass).
//   - k_segstart+k_attn+k_tail fused (per-block binary search of segment bounds).
//   - k_aggcsr gather 8-wide.

typedef unsigned short ushort_t;
typedef __attribute__((ext_vector_type(8))) short bf16x8;   // 8 bf16 (MFMA A/B frag)
typedef __attribute__((ext_vector_type(4))) float floatx4;  // MFMA C/D frag

#define NBLK 128      // edge chunks for hist/place
#define MAXNB 1024    // max buckets (N <= 131072)

// ---------- helpers ----------
__device__ __forceinline__ float b2f(ushort_t u) {
    union { unsigned int i; float f; } v; v.i = ((unsigned int)u) << 16; return v.f;
}
__device__ __forceinline__ ushort_t f2b(float f) {
    union { float f; unsigned int i; } v; v.f = f;
    unsigned int x = v.i;
    return (ushort_t)((x + 0x7FFFu + ((x >> 16) & 1u)) >> 16);   // RTNE
}
__device__ __forceinline__ float gelu_f(float x) {
    return 0.5f * x * (1.0f + erff(x * 0.70710678118654752440f)); // exact gelu
}
__device__ __forceinline__ float waveReduceSum(float v) {
#pragma unroll
    for (int o = 32; o; o >>= 1) v += __shfl_xor(v, o, 64);
    return v;
}
__device__ __forceinline__ float waveReduceMax(float v) {
#pragma unroll
    for (int o = 32; o; o >>= 1) v = fmaxf(v, __shfl_xor(v, o, 64));
    return v;
}
__device__ __forceinline__ int lowerBound(const int* __restrict__ a, int n, int v) {
    int lo = 0, hi = n;
    while (lo < hi) { int mid = (lo + hi) >> 1; if (a[mid] < v) lo = mid + 1; else hi = mid; }
    return lo;
}

// ---------- 0. Wt[n][k] = bf16 concat-transpose of Wl;Wr ----------
__global__ void k_prep(const float* __restrict__ Wl, const float* __restrict__ Wr,
                       ushort_t* __restrict__ Wt) {
    int id = blockIdx.x * 256 + threadIdx.x;   // 128*256 = 32768
    if (id >= 32768) return;
    int n = id >> 8, k = id & 255;
    float v = (k < 128) ? Wl[k * 128 + n] : Wr[(k - 128) * 128 + n];
    Wt[n * 256 + k] = f2b(v);
}

// ---------- 1. h = layernorm(x, w, b) -> bf16  (one wave per row) ----------
__global__ void k_ln1(const float* __restrict__ x, const float* __restrict__ w,
                      const float* __restrict__ b, ushort_t* __restrict__ hb, int N) {
    int row  = (blockIdx.x * blockDim.x + threadIdx.x) >> 6;
    int lane = threadIdx.x & 63;
    if (row >= N) return;
    size_t base = (size_t)row * 128;
    float2 xv = ((const float2*)(x + base))[lane];
    float v0 = xv.x, v1 = xv.y;
    float s  = waveReduceSum(v0 + v1);
    float s2 = waveReduceSum(v0 * v0 + v1 * v1);
    float mu = s * (1.0f / 128.0f);
    float var = s2 * (1.0f / 128.0f) - mu * mu;
    float rstd = 1.0f / sqrtf(var + 1e-5f);
    int d = lane * 2;
    ushort2 ov;
    ov.x = f2b((v0 - mu) * rstd * w[d]     + b[d]);
    ov.y = f2b((v1 - mu) * rstd * w[d + 1] + b[d + 1]);
    ((ushort2*)(hb + base))[lane] = ov;
}

// ---------- 2. fused: deg[dst]++ (global) + per-chunk bucket hist (LDS) ----------
__global__ void __launch_bounds__(256) k_deghist(
    const int* __restrict__ ei, int* __restrict__ deg, int* __restrict__ bhist,
    int E, int nb, int chunk) {
    __shared__ int hist[MAXNB];
    int blk = blockIdx.x, t = threadIdx.x;
    for (int i = t; i < nb; i += 256) hist[i] = 0;
    __syncthreads();
    int e0 = blk * chunk, e1 = min(e0 + chunk, E);
    for (int e = e0 + t; e < e1; e += 256) {
        int d = ei[E + e];
        atomicAdd(&deg[d], 1);          // 50K counters: uncontended
        atomicAdd(&hist[d >> 7], 1);    // LDS
    }
    __syncthreads();
    for (int i = t; i < nb; i += 256) bhist[i * NBLK + blk] = hist[i];
}

// ---------- 3. scan: chunk sums -> chunk scan -> per-element cursor (row starts) -----
__global__ void k_chunksum(const int* __restrict__ deg, int* __restrict__ csum, int N) {
    int i = blockIdx.x * 256 + threadIdx.x;
    int v = (i < N) ? deg[i] : 0;
#pragma unroll
    for (int o = 32; o; o >>= 1) v += __shfl_xor(v, o, 64);
    __shared__ int buf[4];
    int lane = threadIdx.x & 63, wv = threadIdx.x >> 6;
    if (lane == 0) buf[wv] = v;
    __syncthreads();
    if (threadIdx.x == 0) csum[blockIdx.x] = buf[0] + buf[1] + buf[2] + buf[3];
}
__global__ void k_chunkscan(const int* __restrict__ csum, int* __restrict__ coff, int nch) {
    int t = threadIdx.x;
    int v = (t < nch) ? csum[t] : 0;
    __shared__ int sb[256];
    sb[t] = v; __syncthreads();
    for (int o = 1; o < 256; o <<= 1) {
        int a = (t >= o) ? sb[t - o] : 0;
        __syncthreads();
        sb[t] += a;
        __syncthreads();
    }
    coff[t] = sb[t] - v;    // exclusive
}
__global__ void k_cursor(const int* __restrict__ deg, const int* __restrict__ coff,
                         int* __restrict__ cursor, int N) {
    int t = threadIdx.x;
    int i = blockIdx.x * 256 + t;
    int v = (i < N) ? deg[i] : 0;
    __shared__ int sb[256];
    sb[t] = v; __syncthreads();
    for (int o = 1; o < 256; o <<= 1) {
        int a = (t >= o) ? sb[t - o] : 0;
        __syncthreads();
        sb[t] += a;
        __syncthreads();
    }
    if (i < N) cursor[i] = sb[t] - v + coff[blockIdx.x];   // exclusive scan = row start
}

// ---------- 4b. scan per bucket over chunks: boff[blk*nb + b] ----------
__global__ void __launch_bounds__(256) k_bscan(
    const int* __restrict__ bhist, const int* __restrict__ cursor,
    int* __restrict__ boff, int nb) {
    int t = threadIdx.x;
    for (int b = t; b < nb; b += 256) {
        int run = cursor[b << 7];            // b<<7 < N by nb construction
        const int* row = bhist + b * NBLK;   // contiguous 512 B
#pragma unroll 8
        for (int blk = 0; blk < NBLK; blk++) {
            boff[blk * nb + b] = run;
            run += row[blk];
        }
    }
}

// ---------- 4c. placement: LDS cursors per chunk, dense per-(chunk,bucket) runs ------
__global__ void __launch_bounds__(256) k_bplace(
    const int* __restrict__ ei, const int* __restrict__ boff,
    unsigned int* __restrict__ packed, int E, int nb, int chunk) {
    __shared__ int lcur[MAXNB];
    int blk = blockIdx.x, t = threadIdx.x;
    for (int i = t; i < nb; i += 256) lcur[i] = boff[blk * nb + i];
    __syncthreads();
    int e0 = blk * chunk, e1 = min(e0 + chunk, E);
    for (int e = e0 + t; e < e1; e += 256) {
        int s = ei[e], d = ei[E + e];
        int pos = atomicAdd(&lcur[d >> 7], 1);      // LDS atomic
        packed[pos] = ((unsigned int)(d & 127) << 25) | (unsigned int)s;
    }
}

// ---------- 4d. per-bucket placement into nbr (8 KB region, LDS node cursors) --------
__global__ void __launch_bounds__(256) k_bsort(
    const unsigned int* __restrict__ packed, const int* __restrict__ cursor,
    int* __restrict__ nbr, int N, int E) {
    __shared__ int lcur[128];
    int b = blockIdx.x, t = threadIdx.x;
    int node0 = b << 7;
    if (t < 128) {
        int node = node0 + t;
        lcur[t] = (node < N) ? cursor[node] : 0;
    }
    __syncthreads();
    int gstart = cursor[node0];
    int next = node0 + 128;
    int gend = (next < N) ? cursor[next] : E;
    for (int i = gstart + t; i < gend; i += 256) {
        unsigned int p = packed[i];
        int pos = atomicAdd(&lcur[p >> 25], 1);     // LDS atomic
        nbr[pos] = (int)(p & 0x1FFFFFFu);
    }
}

// ---------- 5. CSR gather + mean, bf16 (one wave per node; 8-wide MLP) ----------
__global__ void k_aggcsr(const ushort_t* __restrict__ hb, const int* __restrict__ cursor,
                         const int* __restrict__ deg, const int* __restrict__ nbr,
                         ushort_t* __restrict__ meanb, int N) {
    int node = (blockIdx.x * blockDim.x + threadIdx.x) >> 6;
    int lane = threadIdx.x & 63;
    if (node >= N) return;
    int dg = deg[node];
    int st = cursor[node];
    float a0 = 0.f, a1 = 0.f;
    int j = 0;
    for (; j + 8 <= dg; j += 8) {        // 8 independent row gathers in flight
        int s0 = nbr[st + j],     s1 = nbr[st + j + 1];
        int s2 = nbr[st + j + 2], s3 = nbr[st + j + 3];
        int s4 = nbr[st + j + 4], s5 = nbr[st + j + 5];
        int s6 = nbr[st + j + 6], s7 = nbr[st + j + 7];
        ushort2 v0 = ((const ushort2*)(hb + (size_t)s0 * 128))[lane];
        ushort2 v1 = ((const ushort2*)(hb + (size_t)s1 * 128))[lane];
        ushort2 v2 = ((const ushort2*)(hb + (size_t)s2 * 128))[lane];
        ushort2 v3 = ((const ushort2*)(hb + (size_t)s3 * 128))[lane];
        ushort2 v4 = ((const ushort2*)(hb + (size_t)s4 * 128))[lane];
        ushort2 v5 = ((const ushort2*)(hb + (size_t)s5 * 128))[lane];
        ushort2 v6 = ((const ushort2*)(hb + (size_t)s6 * 128))[lane];
        ushort2 v7 = ((const ushort2*)(hb + (size_t)s7 * 128))[lane];
        a0 += b2f(v0.x) + b2f(v1.x) + b2f(v2.x) + b2f(v3.x)
            + b2f(v4.x) + b2f(v5.x) + b2f(v6.x) + b2f(v7.x);
        a1 += b2f(v0.y) + b2f(v1.y) + b2f(v2.y) + b2f(v3.y)
            + b2f(v4.y) + b2f(v5.y) + b2f(v6.y) + b2f(v7.y);
    }
    for (; j + 4 <= dg; j += 4) {
        int s0 = nbr[st + j],     s1 = nbr[st + j + 1];
        int s2 = nbr[st + j + 2], s3 = nbr[st + j + 3];
        ushort2 v0 = ((const ushort2*)(hb + (size_t)s0 * 128))[lane];
        ushort2 v1 = ((const ushort2*)(hb + (size_t)s1 * 128))[lane];
        ushort2 v2 = ((const ushort2*)(hb + (size_t)s2 * 128))[lane];
        ushort2 v3 = ((const ushort2*)(hb + (size_t)s3 * 128))[lane];
        a0 += b2f(v0.x) + b2f(v1.x) + b2f(v2.x) + b2f(v3.x);
        a1 += b2f(v0.y) + b2f(v1.y) + b2f(v2.y) + b2f(v3.y);
    }
    for (; j < dg; j++) {
        int s = nbr[st + j];
        ushort2 v = ((const ushort2*)(hb + (size_t)s * 128))[lane];
        a0 += b2f(v.x); a1 += b2f(v.y);
    }
    float inv = 1.0f / fmaxf((float)dg, 1.0f);
    ushort2 ov; ov.x = f2b(a0 * inv); ov.y = f2b(a1 * inv);
    ((ushort2*)(meanb + (size_t)node * 128))[lane] = ov;
}

// ---------- 6. MFMA: h2 = [mean|h] @ [Wl;Wr] + b_l ; LN ; gelu ; gate ----------
__global__ void __launch_bounds__(256) k_gemm(
    const ushort_t* __restrict__ meanb, ushort_t* __restrict__ hb,
    const ushort_t* __restrict__ Wt, const float* __restrict__ bl,
    const float* __restrict__ lnw, const float* __restrict__ lnb,
    const float* __restrict__ gw, const float* __restrict__ gb,
    float* __restrict__ gate, int N) {
    __shared__ ushort_t A[16][264];   // [m][k], pad 264
    __shared__ float H2[16][132];
    int t = threadIdx.x;
    int row0 = blockIdx.x * 16;
    {   // stage A tile
        int r = t >> 4, i = t & 15;
        int row = row0 + r; if (row >= N) row = N - 1;
        *(bf16x8*)&A[r][i * 8]       = *(const bf16x8*)(meanb + (size_t)row * 128 + i * 8);
        *(bf16x8*)&A[r][128 + i * 8] = *(const bf16x8*)(hb    + (size_t)row * 128 + i * 8);
    }
    __syncthreads();
    int w = t >> 6, l = t & 63;
    int m16 = l & 15, quad = l >> 4;
    int n0 = w * 32 + m16;
    int n1 = n0 + 16;
    floatx4 acc0 = {0.f, 0.f, 0.f, 0.f}, acc1 = {0.f, 0.f, 0.f, 0.f};
    for (int ks = 0; ks < 256; ks += 32) {
        bf16x8 a  = *(const bf16x8*)&A[m16][ks + quad * 8];
        bf16x8 b0 = *(const bf16x8*)(Wt + (size_t)n0 * 256 + ks + quad * 8);
        bf16x8 b1 = *(const bf16x8*)(Wt + (size_t)n1 * 256 + ks + quad * 8);
        acc0 = __builtin_amdgcn_mfma_f32_16x16x32_bf16(a, b0, acc0, 0, 0, 0);
        acc1 = __builtin_amdgcn_mfma_f32_16x16x32_bf16(a, b1, acc1, 0, 0, 0);
    }
#pragma unroll
    for (int i = 0; i < 4; i++) {
        H2[quad * 4 + i][n0] = acc0[i];
        H2[quad * 4 + i][n1] = acc1[i];
    }
    __syncthreads();
    int d = l * 2;
    float bb0 = bl[d],  bb1 = bl[d + 1];
    float lw0 = lnw[d], lw1 = lnw[d + 1];
    float lb0 = lnb[d], lb1 = lnb[d + 1];
    float gw0 = gw[d],  gw1 = gw[d + 1];
    float gbias = gb[0];
#pragma unroll
    for (int rr = 0; rr < 4; rr++) {
        int r = w * 4 + rr;
        int row = row0 + r;
        if (row >= N) break;
        float v0 = H2[r][d] + bb0, v1 = H2[r][d + 1] + bb1;
        float s  = waveReduceSum(v0 + v1);
        float s2 = waveReduceSum(v0 * v0 + v1 * v1);
        float mu = s * (1.f / 128.f);
        float var = s2 * (1.f / 128.f) - mu * mu;
        float rstd = 1.0f / sqrtf(var + 1e-5f);
        float g0 = gelu_f((v0 - mu) * rstd * lw0 + lb0);
        float g1 = gelu_f((v1 - mu) * rstd * lw1 + lb1);
        float gp = waveReduceSum(g0 * gw0 + g1 * gw1);
        ushort2 ov; ov.x = f2b(g0); ov.y = f2b(g1);
        ((ushort2*)(hb + (size_t)row * 128))[l] = ov;    // h3 in place (bf16)
        if (l == 0) gate[row] = gp + gbias;
    }
}

// ---------- 7. fused: segment bounds (binary search) + softmax pool + head ----------
__global__ void __launch_bounds__(128) k_attntail(
    const float* __restrict__ gate, const ushort_t* __restrict__ h3b,
    const int* __restrict__ batch,
    const float* __restrict__ text, const float* __restrict__ feats,
    const float* __restrict__ msgW, const float* __restrict__ msgb,
    const float* __restrict__ featW, const float* __restrict__ featb,
    const float* __restrict__ gwt, const float* __restrict__ mixw,
    const float* __restrict__ mixb, const float* __restrict__ fc1W,
    const float* __restrict__ fc1b,
    float* __restrict__ ge_out, float* __restrict__ attn_out,
    float* __restrict__ logits, int N, int G) {
    int g = blockIdx.x, t = threadIdx.x;
    __shared__ int sbound[2];
    __shared__ float wbuf[2];
    __shared__ float pbuf[128];
    __shared__ float txt[768];
    __shared__ float rbuf[4];
    if (t < 2) sbound[t] = lowerBound(batch, N, g + t);
    for (int i = t; i < 768; i += 128) txt[i] = text[(size_t)g * 768 + i];
    __syncthreads();
    int s0 = sbound[0], s1 = sbound[1];
    int lane = t & 63, wv = t >> 6;
    float acc = 0.f;
    if (s1 > s0) {                       // block-uniform branch
        float m = -3.0e38f;
        for (int i = s0 + t; i < s1; i += 128) m = fmaxf(m, gate[i]);
        m = waveReduceMax(m);
        if (lane == 0) wbuf[wv] = m;
        __syncthreads();
        m = fmaxf(wbuf[0], wbuf[1]);
        __syncthreads();
        float dsum = 0.f;
        for (int i = s0 + t; i < s1; i += 128) dsum += expf(gate[i] - m);
        dsum = waveReduceSum(dsum);
        if (lane == 0) wbuf[wv] = dsum;
        __syncthreads();
        float inv = 1.0f / (wbuf[0] + wbuf[1]);
        for (int base = s0; base < s1; base += 128) {
            int n = min(128, s1 - base);
            __syncthreads();
            if (t < n) {
                float p = expf(gate[base + t] - m) * inv;
                pbuf[t] = p;
                attn_out[base + t] = p;
            }
            __syncthreads();
            for (int j = 0; j < n; j++)
                acc += pbuf[j] * b2f(h3b[(size_t)(base + j) * 128 + t]);
        }
    }
    ge_out[(size_t)g * 128 + t] = acc;
    // ---- head ----
    float am = msgb[t];
    for (int k = 0; k < 768; k += 4) {
        float4 a = *(const float4*)&txt[k];
        am += a.x * msgW[(k + 0) * 128 + t] + a.y * msgW[(k + 1) * 128 + t]
            + a.z * msgW[(k + 2) * 128 + t] + a.w * msgW[(k + 3) * 128 + t];
    }
    float me = gelu_f(am);
    float af = featb[t];
#pragma unroll
    for (int k = 0; k < 14; k++) af += feats[g * 14 + k] * featW[k * 128 + t];
    float fe = gelu_f(af);
    float e0 = gwt[0] * acc;
    float ps = e0 + me + fe, ps2 = e0 * e0 + me * me + fe * fe;
    float r1 = waveReduceSum(ps), r2 = waveReduceSum(ps2);
    __syncthreads();
    if (lane == 0) { rbuf[wv] = r1; rbuf[2 + wv] = r2; }
    __syncthreads();
    float S = rbuf[0] + rbuf[1], S2 = rbuf[2] + rbuf[3];
    float mu = S * (1.f / 384.f);
    float var = S2 * (1.f / 384.f) - mu * mu;
    float rstd = 1.0f / sqrtf(var + 1e-5f);
    float n0 = (e0 - mu) * rstd * mixw[t]       + mixb[t];
    float n1 = (me - mu) * rstd * mixw[128 + t] + mixb[128 + t];
    float n2 = (fe - mu) * rstd * mixw[256 + t] + mixb[256 + t];
    float lp = n0 * fc1W[t] + n1 * fc1W[128 + t] + n2 * fc1W[256 + t];
    float r3 = waveReduceSum(lp);
    __syncthreads();
    if (lane == 0) rbuf[wv] = r3;
    __syncthreads();
    if (t == 0) logits[g] = rbuf[0] + rbuf[1] + fc1b[0];
}

// ---------- launch ----------
extern "C" void kernel_launch(void* const* d_in, const int* in_sizes, int n_in,
                              void* d_out, int out_size, void* d_ws, size_t ws_size,
                              hipStream_t stream) {
    const float* x     = (const float*)d_in[0];
    const int*   ei    = (const int*)d_in[1];
    const int*   batch = (const int*)d_in[2];
    const float* text  = (const float*)d_in[4];
    const float* feats = (const float*)d_in[5];
    const float* lnpw  = (const float*)d_in[6];
    const float* lnpb  = (const float*)d_in[7];
    const float* Wl    = (const float*)d_in[8];
    const float* bl    = (const float*)d_in[9];
    const float* Wr    = (const float*)d_in[10];
    const float* lncw  = (const float*)d_in[11];
    const float* lncb  = (const float*)d_in[12];
    const float* gatew = (const float*)d_in[13];
    const float* gateb = (const float*)d_in[14];
    const float* gwt   = (const float*)d_in[15];
    const float* msgW  = (const float*)d_in[16];
    const float* msgb  = (const float*)d_in[17];
    const float* featW = (const float*)d_in[18];
    const float* featb = (const float*)d_in[19];
    const float* mixw  = (const float*)d_in[20];
    const float* mixb  = (const float*)d_in[21];
    const float* fc1W  = (const float*)d_in[22];
    const float* fc1b  = (const float*)d_in[23];

    int N = in_sizes[0] / 128;
    int E = in_sizes[1] / 2;
    int G = in_sizes[4] / 768;

    char* wp = (char*)d_ws;
    auto alloc = [&](size_t bytes) -> char* {
        char* p = wp; wp += (bytes + 255) & ~(size_t)255; return p;
    };
    ushort_t* hb     = (ushort_t*)alloc((size_t)N * 128 * 2);   // h -> h3 in place (bf16)
    ushort_t* meanb  = (ushort_t*)alloc((size_t)N * 128 * 2);
    ushort_t* Wt     = (ushort_t*)alloc(128 * 256 * 2);
    float*    gate   = (float*)alloc((size_t)N * 4);
    int*      deg    = (int*)alloc((size_t)N * 4);
    int*      cursor = (int*)alloc((size_t)N * 4);
    int*      nbr    = (int*)alloc((size_t)E * 4);
    unsigned int* packed = (unsigned int*)alloc((size_t)E * 4);
    int*      csum   = (int*)alloc(1024 * 4);
    int*      coff   = (int*)alloc(1024 * 4);

    int nch = (N + 255) / 256;   // 196 <= 256: one chunkscan block suffices
    int nb  = (N + 127) / 128;   // buckets of 128 nodes (391 for N=50000)
    int chunk = (E + NBLK - 1) / NBLK;

    int* bhist = (int*)alloc((size_t)nb * NBLK * 4);   // [b][blk]
    int* boff  = (int*)alloc((size_t)NBLK * nb * 4);   // [blk][b]

    // OUTPUTS fp32, flat in return order:
    float* logits_out = (float*)d_out;                 // [G, 1]
    float* ge_out     = logits_out + G;                // [G, 128]
    float* attn_out   = ge_out + (size_t)G * 128;      // [N, 1]

    hipMemsetAsync(deg, 0, (size_t)N * 4, stream);

    k_prep     <<<128,               256, 0, stream>>>(Wl, Wr, Wt);
    k_ln1      <<<(N + 3) / 4,       256, 0, stream>>>(x, lnpw, lnpb, hb, N);
    k_deghist  <<<NBLK,              256, 0, stream>>>(ei, deg, bhist, E, nb, chunk);
    k_chunksum <<<nch,               256, 0, stream>>>(deg, csum, N);
    k_chunkscan<<<1,                 256, 0, stream>>>(csum, coff, nch);
    k_cursor   <<<nch,               256, 0, stream>>>(deg, coff, cursor, N);
    k_bscan    <<<1,                 256, 0, stream>>>(bhist, cursor, boff, nb);
    k_bplace   <<<NBLK,              256, 0, stream>>>(ei, boff, packed, E, nb, chunk);
    k_bsort    <<<nb,                256, 0, stream>>>(packed, cursor, nbr, N, E);
    k_aggcsr   <<<(N + 3) / 4,       256, 0, stream>>>(hb, cursor, deg, nbr, meanb, N);
    k_gemm     <<<(N + 15) / 16,     256, 0, stream>>>(meanb, hb, Wt, bl, lncw, lncb,
                                                       gatew, gateb, gate, N);
    k_attntail <<<G,                 128, 0, stream>>>(gate, hb, batch, text, feats,
                                                       msgW, msgb, featW, featb, gwt,
                                                       mixw, mixb, fc1W, fc1b,
                                                       ge_out, attn_out, logits_out, N, G);
}